// Round 6
// baseline (78.872 us; speedup 1.0000x reference)
//
#include <hip/hip_runtime.h>

static constexpr int B = 128;
static constexpr int G = 64;
static constexpr int P = 8732;
static constexpr float EPS = 1e-5f;
static constexpr float IOU_THR = 0.5f;

// Bitwise-numpy-identical IoU: no contraction, IEEE div, numpy association order:
//   lt=max, rb=min, hw=max(rb-lt,0), ov=hw0*hw1, den=((ga+pa)-ov)+eps, ov/den
// gx*/ga arrive as wave-uniform (SGPR) operands: each VALU op reads <=1 SGPR.
__device__ __forceinline__ float iou_exact(
    float gx1, float gy1, float gx2, float gy2, float ga,
    float px1, float py1, float px2, float py2, float pa)
{
    float ltx = fmaxf(gx1, px1), lty = fmaxf(gy1, py1);
    float rbx = fminf(gx2, px2), rby = fminf(gy2, py2);
    float ow  = fmaxf(__fsub_rn(rbx, ltx), 0.0f);
    float oh  = fmaxf(__fsub_rn(rby, lty), 0.0f);
    float ov  = __fmul_rn(ow, oh);
    float den = __fadd_rn(__fsub_rn(__fadd_rn(ga, pa), ov), EPS);
    return __fdiv_rn(ov, den);
}

__device__ __forceinline__ void encode_store(
    float* out_loc, float* out_lab, int b, int p,
    float4 gb, float4 pr, int lab)
{
    float cx = (gb.x + gb.z) * 0.5f;
    float cy = (gb.y + gb.w) * 0.5f;
    float w  = gb.z - gb.x;
    float h  = gb.w - gb.y;
    float4 loc;
    loc.x = (cx - pr.x) / (pr.z * 0.1f);
    loc.y = (cy - pr.y) / (pr.w * 0.1f);
    loc.z = logf(w / pr.z) / 0.2f;
    loc.w = logf(h / pr.w) / 0.2f;
    *(float4*)(out_loc + (size_t)(b * P + p) * 4) = loc;
    out_lab[(size_t)b * P + p] = (float)lab;
}

// Prep: gt_ext[b][g] = {x1,y1,x2,y2,area,0,0,0} (stride 8 for aligned s_load),
// and zero the packed atomicMax array (monotone; 0xAA poison would stick).
__global__ __launch_bounds__(64) void k_prep(
    const float* __restrict__ gt_boxes,
    float* __restrict__ gt_ext,
    unsigned long long* __restrict__ packed)
{
    const int b = blockIdx.x;
    const int g = threadIdx.x;
    const int i = b * G + g;
    float4 gb = *(const float4*)(gt_boxes + (size_t)i * 4);
    float ga = __fmul_rn(fmaxf(__fsub_rn(gb.z, gb.x), 0.0f),
                         fmaxf(__fsub_rn(gb.w, gb.y), 0.0f));
    *(float4*)(gt_ext + (size_t)i * 8)     = gb;
    *(float4*)(gt_ext + (size_t)i * 8 + 4) = make_float4(ga, 0.f, 0.f, 0.f);
    packed[i] = 0ull;
}

// Fused single pass over all B*G*P IoUs. gt data for each 8-g sub-chunk is
// batch-loaded into SGPR-resident locals BEFORE its 8 IoU iterations, so the
// unrolled inner stream is pure VALU + one ds_write — no in-loop SMEM/waits.
__global__ __launch_bounds__(256, 8) void k_fused(
    const int*   __restrict__ gt_labels,      // [B,G]
    const float* __restrict__ priors,         // [P,4] center
    const float* __restrict__ gt_ext,         // [B,G,8]
    unsigned long long* __restrict__ packed,  // [B,G]
    float* __restrict__ out_loc,              // [B,P,4]
    float* __restrict__ out_lab)              // [B,P]
{
    __shared__ float4 s_gt[G];                 // final divergent gather only
    __shared__ unsigned long long s_red[G];
    __shared__ int   s_lab[G];
    __shared__ float s_iou[256][17];           // odd stride: 2-way alias = free

    const int b = blockIdx.y;
    const int t = threadIdx.x;
    const int pbase = blockIdx.x * 256;
    const int p = pbase + t;
    const bool valid = p < P;

    const float* __restrict__ ge = gt_ext + (size_t)b * G * 8;  // uniform base

    if (t < G) {
        s_gt[t]  = *(const float4*)(ge + (size_t)t * 8);
        s_lab[t] = gt_labels[b * G + t];
        s_red[t] = 0ull;
    }
    __syncthreads();

    // Invalid lanes get a degenerate zero prior -> iou == 0.0f exactly for all
    // g (ov=0, den>0). Invalid rows are the largest row indices of the tail
    // block, so ascending strict-> scans and the ~p packing lose every tie to
    // valid rows. No per-iteration predication needed.
    float4 pr = make_float4(0.f, 0.f, 0.f, 0.f);
    if (valid) pr = *(const float4*)(priors + (size_t)p * 4);
    float hw = __fmul_rn(pr.z, 0.5f), hh = __fmul_rn(pr.w, 0.5f);
    float px1 = __fsub_rn(pr.x, hw), py1 = __fsub_rn(pr.y, hh);
    float px2 = __fadd_rn(pr.x, hw), py2 = __fadd_rn(pr.y, hh);
    float pa  = __fmul_rn(fmaxf(__fsub_rn(px2, px1), 0.0f),
                          fmaxf(__fsub_rn(py2, py1), 0.0f));

    float bestIou = -1.0f;
    int   bestG   = 0;

    for (int q = 0; q < 4; ++q) {
        const int gbase = q * 16;
        // phase1: 16 ious in two 8-g sub-chunks; gt batch-loaded first.
#pragma unroll
        for (int h = 0; h < 2; ++h) {
            float4 gq[8];
            float  gar[8];
#pragma unroll
            for (int k = 0; k < 8; ++k) {
                const int g = gbase + h * 8 + k;
                gq[k]  = *(const float4*)(ge + (size_t)g * 8);   // s_load x4
                gar[k] = ge[(size_t)g * 8 + 4];                  // s_load
            }
#pragma unroll
            for (int k = 0; k < 8; ++k) {
                const int g = gbase + h * 8 + k;
                float iou = iou_exact(gq[k].x, gq[k].y, gq[k].z, gq[k].w,
                                      gar[k], px1, py1, px2, py2, pa);
                s_iou[t][h * 8 + k] = iou;
                if (iou > bestIou) { bestIou = iou; bestG = g; }  // first-g ties
            }
        }
        __syncthreads();

        // phase2: per-g argmax over this block's 256 p's.
        // 16 threads per column (t&15 = col, t>>4 = row-group of 16); ascending
        // rows + strict > = smallest p wins ties; cross-thread/-block merge via
        // packed (iou<<32)|(~p) atomicMax (order-independent, deterministic).
        {
            const int c  = t & 15;
            const int r0 = (t >> 4) * 16;
            float bv = -0.5f;
            int   br = 0;
#pragma unroll
            for (int j = 0; j < 16; ++j) {
                float v = s_iou[r0 + j][c];
                if (v > bv) { bv = v; br = r0 + j; }
            }
            unsigned long long key =
                ((unsigned long long)__float_as_uint(bv) << 32) |
                (unsigned long long)(0xFFFFFFFFu - (unsigned)(pbase + br));
            atomicMax(&s_red[gbase + c], key);
        }
        __syncthreads();
    }

    if (t < G) {
        atomicMax(&packed[(size_t)b * G + t], s_red[t]);
    }

    if (valid) {
        int lab = (bestIou < IOU_THR) ? 0 : s_lab[bestG];
        encode_store(out_loc, out_lab, b, p, s_gt[bestG], pr, lab);
    }
}

// Force-assign fixup: each gt overwrites its best prior; duplicate p resolved
// last-g-wins (matches jnp .at[].set scatter order).
__global__ __launch_bounds__(64) void k_fixup(
    const float* __restrict__ gt_boxes,
    const int*   __restrict__ gt_labels,
    const float* __restrict__ priors,
    const unsigned long long* __restrict__ packed,
    float* __restrict__ out_loc,
    float* __restrict__ out_lab)
{
    __shared__ int s_p[G];
    const int b = blockIdx.x;
    const int g = threadIdx.x;

    unsigned long long key = packed[(size_t)b * G + g];
    int p = (int)(0xFFFFFFFFu - (unsigned)(key & 0xFFFFFFFFull));
    s_p[g] = p;
    __syncthreads();

    bool win = true;
    for (int g2 = g + 1; g2 < G; ++g2)
        if (s_p[g2] == p) { win = false; break; }

    if (win) {
        float4 gb = *(const float4*)(gt_boxes + (size_t)(b * G + g) * 4);
        float4 pr = *(const float4*)(priors + (size_t)p * 4);
        int lab = gt_labels[b * G + g];   // forced: iou=2.0 >= thr, label kept
        encode_store(out_loc, out_lab, b, p, gb, pr, lab);
    }
}

extern "C" void kernel_launch(void* const* d_in, const int* in_sizes, int n_in,
                              void* d_out, int out_size, void* d_ws, size_t ws_size,
                              hipStream_t stream)
{
    const float* gt_boxes  = (const float*)d_in[0];
    const int*   gt_labels = (const int*)d_in[1];
    const float* priors    = (const float*)d_in[2];

    float* out_loc = (float*)d_out;                   // B*P*4 floats
    float* out_lab = out_loc + (size_t)B * P * 4;     // B*P floats

    // ws layout: packed [B*G] u64 (64 KB) | gt_ext [B*G*8] f32 (256 KB)
    unsigned long long* packed = (unsigned long long*)d_ws;
    float* gt_ext = (float*)((char*)d_ws + (size_t)B * G * sizeof(unsigned long long));

    k_prep<<<dim3(B), 64, 0, stream>>>(gt_boxes, gt_ext, packed);

    k_fused<<<dim3((P + 255) / 256, B), 256, 0, stream>>>(
        gt_labels, priors, gt_ext, packed, out_loc, out_lab);

    k_fixup<<<dim3(B), 64, 0, stream>>>(
        gt_boxes, gt_labels, priors, packed, out_loc, out_lab);
}

// Round 7
// 71.973 us; speedup vs baseline: 1.0959x; 1.0959x over previous
//
#include <hip/hip_runtime.h>

static constexpr int B = 128;
static constexpr int G = 64;
static constexpr int P = 8732;
static constexpr float EPS = 1e-5f;
static constexpr float IOU_THR = 0.5f;

// Correctly-rounded f32 division for guaranteed-normal operands, 6 ops, no VCC.
// Identical bits to IEEE (numpy) division for our range: d in [1e-5, 2.5],
// x == 0 or x in [~1e-20, 1] (all normal; x=0 -> +0 exactly). This is AMD's own
// CR div lowering minus the exponent-scaling machinery (div_scale/div_fmas/
// div_fixup) that only matters for denormal/extreme-exponent inputs.
// Markstein: r1 within 0.5 ulp of 1/d after one NR from <=1-ulp v_rcp_f32 =>
// q correctly rounded.
__device__ __forceinline__ float div_rn_normal(float x, float d)
{
    float r0  = __builtin_amdgcn_rcpf(d);
    float e   = __fmaf_rn(-d, r0, 1.0f);
    float r1  = __fmaf_rn(e, r0, r0);
    float q0  = __fmul_rn(x, r1);
    float rem = __fmaf_rn(-d, q0, x);
    return __fmaf_rn(rem, r1, q0);
}

// Bitwise-numpy-identical IoU: no contraction, CR div, numpy association order:
//   lt=max, rb=min, hw=max(rb-lt,0), ov=hw0*hw1, den=((ga+pa)-ov)+eps, ov/den
__device__ __forceinline__ float iou_exact(
    float gx1, float gy1, float gx2, float gy2, float ga,
    float px1, float py1, float px2, float py2, float pa)
{
    float ltx = fmaxf(gx1, px1), lty = fmaxf(gy1, py1);
    float rbx = fminf(gx2, px2), rby = fminf(gy2, py2);
    float ow  = fmaxf(__fsub_rn(rbx, ltx), 0.0f);
    float oh  = fmaxf(__fsub_rn(rby, lty), 0.0f);
    float ov  = __fmul_rn(ow, oh);
    float den = __fadd_rn(__fsub_rn(__fadd_rn(ga, pa), ov), EPS);
    return div_rn_normal(ov, den);
}

__device__ __forceinline__ void encode_store(
    float* out_loc, float* out_lab, int b, int p,
    float4 gb, float4 pr, int lab)
{
    float cx = (gb.x + gb.z) * 0.5f;
    float cy = (gb.y + gb.w) * 0.5f;
    float w  = gb.z - gb.x;
    float h  = gb.w - gb.y;
    float4 loc;
    loc.x = (cx - pr.x) / (pr.z * 0.1f);
    loc.y = (cy - pr.y) / (pr.w * 0.1f);
    loc.z = logf(w / pr.z) / 0.2f;
    loc.w = logf(h / pr.w) / 0.2f;
    *(float4*)(out_loc + (size_t)(b * P + p) * 4) = loc;
    out_lab[(size_t)b * P + p] = (float)lab;
}

// Prep: gt_ext[b][g] = {x1,y1,x2,y2,area,0,0,0} (stride 8 for aligned s_load),
// and zero the packed atomicMax array (monotone; 0xAA poison would stick).
__global__ __launch_bounds__(64) void k_prep(
    const float* __restrict__ gt_boxes,
    float* __restrict__ gt_ext,
    unsigned long long* __restrict__ packed)
{
    const int b = blockIdx.x;
    const int g = threadIdx.x;
    const int i = b * G + g;
    float4 gb = *(const float4*)(gt_boxes + (size_t)i * 4);
    float ga = __fmul_rn(fmaxf(__fsub_rn(gb.z, gb.x), 0.0f),
                         fmaxf(__fsub_rn(gb.w, gb.y), 0.0f));
    *(float4*)(gt_ext + (size_t)i * 8)     = gb;
    *(float4*)(gt_ext + (size_t)i * 8 + 4) = make_float4(ga, 0.f, 0.f, 0.f);
    packed[i] = 0ull;
}

// Fused single pass over all B*G*P IoUs. gt data batch-loaded to SGPRs per
// 8-g sub-chunk; inner stream is pure VALU + one ds_write per iteration.
__global__ __launch_bounds__(256, 8) void k_fused(
    const int*   __restrict__ gt_labels,      // [B,G]
    const float* __restrict__ priors,         // [P,4] center
    const float* __restrict__ gt_ext,         // [B,G,8]
    unsigned long long* __restrict__ packed,  // [B,G]
    float* __restrict__ out_loc,              // [B,P,4]
    float* __restrict__ out_lab)              // [B,P]
{
    __shared__ float4 s_gt[G];                 // final divergent gather only
    __shared__ unsigned long long s_red[G];
    __shared__ int   s_lab[G];
    __shared__ float s_iou[256][17];           // odd stride: 2-way alias = free

    const int b = blockIdx.y;
    const int t = threadIdx.x;
    const int pbase = blockIdx.x * 256;
    const int p = pbase + t;
    const bool valid = p < P;

    const float* __restrict__ ge = gt_ext + (size_t)b * G * 8;  // uniform base

    if (t < G) {
        s_gt[t]  = *(const float4*)(ge + (size_t)t * 8);
        s_lab[t] = gt_labels[b * G + t];
        s_red[t] = 0ull;
    }
    __syncthreads();

    // Invalid lanes get a degenerate zero prior -> iou == 0.0f exactly for all
    // g (ov=0, den>0). Invalid rows are the largest row indices of the tail
    // block, so ascending strict-> scans and the ~p packing lose every tie to
    // valid rows. No per-iteration predication needed.
    float4 pr = make_float4(0.f, 0.f, 0.f, 0.f);
    if (valid) pr = *(const float4*)(priors + (size_t)p * 4);
    float hw = __fmul_rn(pr.z, 0.5f), hh = __fmul_rn(pr.w, 0.5f);
    float px1 = __fsub_rn(pr.x, hw), py1 = __fsub_rn(pr.y, hh);
    float px2 = __fadd_rn(pr.x, hw), py2 = __fadd_rn(pr.y, hh);
    float pa  = __fmul_rn(fmaxf(__fsub_rn(px2, px1), 0.0f),
                          fmaxf(__fsub_rn(py2, py1), 0.0f));

    float bestIou = -1.0f;
    int   bestG   = 0;

    for (int q = 0; q < 4; ++q) {
        const int gbase = q * 16;
        // phase1: 16 ious in two 8-g sub-chunks; gt batch-loaded first.
#pragma unroll
        for (int h = 0; h < 2; ++h) {
            float4 gq[8];
            float  gar[8];
#pragma unroll
            for (int k = 0; k < 8; ++k) {
                const int g = gbase + h * 8 + k;
                gq[k]  = *(const float4*)(ge + (size_t)g * 8);   // s_load x4
                gar[k] = ge[(size_t)g * 8 + 4];                  // s_load
            }
#pragma unroll
            for (int k = 0; k < 8; ++k) {
                const int g = gbase + h * 8 + k;
                float iou = iou_exact(gq[k].x, gq[k].y, gq[k].z, gq[k].w,
                                      gar[k], px1, py1, px2, py2, pa);
                s_iou[t][h * 8 + k] = iou;
                if (iou > bestIou) { bestIou = iou; bestG = g; }  // first-g ties
            }
        }
        __syncthreads();

        // phase2: per-g argmax over this block's 256 p's.
        // 16 threads per column (t&15 = col, t>>4 = row-group of 16); ascending
        // rows + strict > = smallest p wins ties; cross-thread/-block merge via
        // packed (iou<<32)|(~p) atomicMax (order-independent, deterministic).
        {
            const int c  = t & 15;
            const int r0 = (t >> 4) * 16;
            float bv = -0.5f;
            int   br = 0;
#pragma unroll
            for (int j = 0; j < 16; ++j) {
                float v = s_iou[r0 + j][c];
                if (v > bv) { bv = v; br = r0 + j; }
            }
            unsigned long long key =
                ((unsigned long long)__float_as_uint(bv) << 32) |
                (unsigned long long)(0xFFFFFFFFu - (unsigned)(pbase + br));
            atomicMax(&s_red[gbase + c], key);
        }
        __syncthreads();
    }

    if (t < G) {
        atomicMax(&packed[(size_t)b * G + t], s_red[t]);
    }

    if (valid) {
        int lab = (bestIou < IOU_THR) ? 0 : s_lab[bestG];
        encode_store(out_loc, out_lab, b, p, s_gt[bestG], pr, lab);
    }
}

// Force-assign fixup: each gt overwrites its best prior; duplicate p resolved
// last-g-wins (matches jnp .at[].set scatter order).
__global__ __launch_bounds__(64) void k_fixup(
    const float* __restrict__ gt_boxes,
    const int*   __restrict__ gt_labels,
    const float* __restrict__ priors,
    const unsigned long long* __restrict__ packed,
    float* __restrict__ out_loc,
    float* __restrict__ out_lab)
{
    __shared__ int s_p[G];
    const int b = blockIdx.x;
    const int g = threadIdx.x;

    unsigned long long key = packed[(size_t)b * G + g];
    int p = (int)(0xFFFFFFFFu - (unsigned)(key & 0xFFFFFFFFull));
    s_p[g] = p;
    __syncthreads();

    bool win = true;
    for (int g2 = g + 1; g2 < G; ++g2)
        if (s_p[g2] == p) { win = false; break; }

    if (win) {
        float4 gb = *(const float4*)(gt_boxes + (size_t)(b * G + g) * 4);
        float4 pr = *(const float4*)(priors + (size_t)p * 4);
        int lab = gt_labels[b * G + g];   // forced: iou=2.0 >= thr, label kept
        encode_store(out_loc, out_lab, b, p, gb, pr, lab);
    }
}

extern "C" void kernel_launch(void* const* d_in, const int* in_sizes, int n_in,
                              void* d_out, int out_size, void* d_ws, size_t ws_size,
                              hipStream_t stream)
{
    const float* gt_boxes  = (const float*)d_in[0];
    const int*   gt_labels = (const int*)d_in[1];
    const float* priors    = (const float*)d_in[2];

    float* out_loc = (float*)d_out;                   // B*P*4 floats
    float* out_lab = out_loc + (size_t)B * P * 4;     // B*P floats

    // ws layout: packed [B*G] u64 (64 KB) | gt_ext [B*G*8] f32 (256 KB)
    unsigned long long* packed = (unsigned long long*)d_ws;
    float* gt_ext = (float*)((char*)d_ws + (size_t)B * G * sizeof(unsigned long long));

    k_prep<<<dim3(B), 64, 0, stream>>>(gt_boxes, gt_ext, packed);

    k_fused<<<dim3((P + 255) / 256, B), 256, 0, stream>>>(
        gt_labels, priors, gt_ext, packed, out_loc, out_lab);

    k_fixup<<<dim3(B), 64, 0, stream>>>(
        gt_boxes, gt_labels, priors, packed, out_loc, out_lab);
}